// Round 10
// baseline (2941.920 us; speedup 1.0000x reference)
//
#include <hip/hip_runtime.h>

// N=1048576 nodes, D=256 feats, G=2048 graphs, batch sorted (int32 on device).
// Out = [graph_embedding (G*256 f32), attention_scores (N f32)].
//
// R8's winning streaming config (NT loads, G*4 blocks, 16x ~32-row contiguous
// wave-slices, 4-deep float4 ring, plain per-wave partial stores) with the
// final kernel FUSED via last-block-done:
//   each block: stream slice -> store partials (R8-verbatim) ->
//   __threadfence(); __syncthreads(); atomicAdd(done[g]); last of 4 blocks
//   acquires and runs the R8 final body for graph g inline (overlapped with
//   other graphs' still-streaming blocks).
// bounds_kernel also zeroes done[] each launch (deterministic under replay).

typedef float f32x4 __attribute__((ext_vector_type(4)));

constexpr int DIM = 256;
constexpr int WSL = 16;                 // wave-slices per graph
constexpr float NEG_CLAMP = -3.4e38f;

__device__ __forceinline__ int lower_bound_i32(const int* __restrict__ a, int n, int v) {
    int lo = 0, hi = n;
    while (lo < hi) {
        int mid = (lo + hi) >> 1;
        if (a[mid] < v) lo = mid + 1; else hi = mid;
    }
    return lo;
}

__global__ void bounds_kernel(const int* __restrict__ batch, int* __restrict__ bounds,
                              int* __restrict__ done, int N, int G) {
    int g = blockIdx.x * blockDim.x + threadIdx.x;
    if (g < G) { bounds[g] = lower_bound_i32(batch, N, g); done[g] = 0; }
    if (g == G) bounds[G] = N;
}

__global__ __launch_bounds__(256, 8)
void fused_kernel(const float* __restrict__ x,
                  const int* __restrict__ bounds,
                  float* __restrict__ pmax,          // [G][WSL][DIM]
                  int* __restrict__ pam,             // [G][WSL][DIM]
                  unsigned int* __restrict__ ptie,   // [G][WSL][64] bitmasks
                  int* __restrict__ done,            // [G]
                  float* __restrict__ emb,
                  float* __restrict__ scores)
{
    const int bid = blockIdx.x;          // g*4 + s
    const int g = bid >> 2;
    const int s = bid & 3;
    const int t = threadIdx.x;
    const int w = t >> 6;
    const int l = t & 63;
    const int wi = s * 4 + w;            // wave-slice 0..15

    const int start = bounds[g];
    const int end   = bounds[g + 1];
    const int len   = end - start;
    const int q     = (len + WSL - 1) / WSL;

    int a = start + wi * q;
    int b = a + q;
    if (a > end) a = end;
    if (b > end) b = end;
    const int n = b - a;

    const float NI = -__builtin_huge_valf();
    float m0 = NI, m1 = NI, m2 = NI, m3 = NI;
    int   a0 = -1, a1 = -1, a2 = -1, a3 = -1;
    unsigned int tieb = 0;

    // row r (relative to a), lane l -> p[r*64]
    const f32x4* __restrict__ p = (const f32x4*)x + (size_t)a * 64 + l;

#define LD(r) __builtin_nontemporal_load(p + (size_t)(r) * 64)
#define UPD4(v, idx) do {                                             \
        bool g0 = (v).x > m0, g1 = (v).y > m1,                        \
             g2 = (v).z > m2, g3 = (v).w > m3;                        \
        tieb |= ((v).x == m0) ? 1u : 0u;                              \
        tieb |= ((v).y == m1) ? 2u : 0u;                              \
        tieb |= ((v).z == m2) ? 4u : 0u;                              \
        tieb |= ((v).w == m3) ? 8u : 0u;                              \
        a0 = g0 ? (idx) : a0;  m0 = g0 ? (v).x : m0;                  \
        a1 = g1 ? (idx) : a1;  m1 = g1 ? (v).y : m1;                  \
        a2 = g2 ? (idx) : a2;  m2 = g2 ? (v).z : m2;                  \
        a3 = g3 ? (idx) : a3;  m3 = g3 ? (v).w : m3;                  \
    } while (0)

    // 4-deep prefetch ring, statically indexed
    f32x4 f0 = (f32x4)(NI), f1 = f0, f2 = f0, f3 = f0;
    if (n > 0) f0 = LD(0);
    if (n > 1) f1 = LD(1);
    if (n > 2) f2 = LD(2);
    if (n > 3) f3 = LD(3);

    int k = 0;
    for (; k + 8 <= n; k += 4) {
        UPD4(f0, a + k + 0);  f0 = LD(k + 4);
        UPD4(f1, a + k + 1);  f1 = LD(k + 5);
        UPD4(f2, a + k + 2);  f2 = LD(k + 6);
        UPD4(f3, a + k + 3);  f3 = LD(k + 7);
    }
    const int rem = n - k;   // 0..7
    if (rem > 0) UPD4(f0, a + k + 0);
    if (rem > 1) UPD4(f1, a + k + 1);
    if (rem > 2) UPD4(f2, a + k + 2);
    if (rem > 3) UPD4(f3, a + k + 3);
    for (int r = k + 4; r < n; ++r) {
        f32x4 v = LD(r);
        UPD4(v, a + r);
    }
#undef UPD4
#undef LD

    // per-wave partial stores (R8-verbatim)
    const size_t base = ((size_t)g * WSL + wi) * DIM + (size_t)l * 4;
    f32x4 mv; mv.x = m0; mv.y = m1; mv.z = m2; mv.w = m3;
    *(f32x4*)(pmax + base) = mv;
    int4 av; av.x = a0; av.y = a1; av.z = a2; av.w = a3;
    *(int4*)(pam + base)   = av;
    ptie[((size_t)g * WSL + wi) * 64 + l] = tieb;

    // ---- last-block-done handoff (fence-fence message passing, G16) ----
    __shared__ int sprev;
    __threadfence();          // release: own partial stores -> device scope
    __syncthreads();          // all threads fenced (barrier drains vmcnt)
    if (t == 0) sprev = atomicAdd(&done[g], 1);
    __syncthreads();
    if (sprev != 3) return;   // not the last of graph g's 4 blocks

    __threadfence();          // acquire: invalidate stale lines before reads

    // ---- finalize graph g (R8 final_kernel body; two-pass partial read) ----
    const size_t pb = (size_t)g * WSL * DIM + t;

    float M = -__builtin_huge_valf();
    #pragma unroll
    for (int i = 0; i < WSL; ++i) M = fmaxf(M, pmax[pb + (size_t)i * DIM]);
    emb[(size_t)g * DIM + t] = fmaxf(M, NEG_CLAMP);

    for (int j = start + t; j < end; j += DIM) scores[j] = 0.0f;
    __syncthreads();          // zeros visible before marking

    bool rescan = false;
    #pragma unroll
    for (int i = 0; i < WSL; ++i) {
        if (pmax[pb + (size_t)i * DIM] == M) {
            const int am = pam[pb + (size_t)i * DIM];
            if (am >= 0) scores[am] = 1.0f;      // duplicate 1.0 stores benign
            rescan = rescan ||
                (((ptie[((size_t)g * WSL + i) * 64 + (t >> 2)] >> (t & 3)) & 1u) != 0u);
        }
    }
    if (rescan) {
        // rare: exact duplicate of a slice's running max in a max-attaining
        // slice; re-scan column t, mark every exact hit of the final max.
        const float* __restrict__ col = x + t;
        for (int j = start; j < end; ++j)
            if (col[(size_t)j * DIM] == M) scores[j] = 1.0f;
    }
    __syncthreads();          // all 1-writes visible before counting

    float cnt = 0.0f;
    for (int j = start + t; j < end; j += DIM) cnt += scores[j];
    for (int off = 32; off > 0; off >>= 1) cnt += __shfl_down(cnt, off, 64);

    __shared__ float sred[4];
    if (l == 0) sred[w] = cnt;
    __syncthreads();
    const float total = sred[0] + sred[1] + sred[2] + sred[3];
    const float inv = 1.0f / fmaxf(total, 1.0f);  // exact: numerator is 0 or 1

    for (int j = start + t; j < end; j += DIM) scores[j] *= inv;
}

extern "C" void kernel_launch(void* const* d_in, const int* in_sizes, int n_in,
                              void* d_out, int out_size, void* d_ws, size_t ws_size,
                              hipStream_t stream) {
    const float* x     = (const float*)d_in[0];
    const int*   batch = (const int*)d_in[1];

    const int N  = in_sizes[1];          // 1048576
    const int Dd = in_sizes[0] / N;      // 256
    const int G  = (out_size - N) / Dd;  // 2048

    float* emb    = (float*)d_out;
    float* scores = (float*)d_out + (size_t)G * Dd;

    // workspace layout (≈75 MB; ws is ~4 GB)
    char* ws = (char*)d_ws;
    int* bounds = (int*)ws;
    size_t off = (((size_t)(G + 1) * sizeof(int)) + 1023) & ~(size_t)1023;
    float* pmax = (float*)(ws + off);  off += (size_t)G * WSL * DIM * sizeof(float);
    int*   pam  = (int*)(ws + off);    off += (size_t)G * WSL * DIM * sizeof(int);
    unsigned int* ptie = (unsigned int*)(ws + off);
    off += (size_t)G * WSL * 64 * sizeof(unsigned int);
    int* done = (int*)(ws + off);

    bounds_kernel<<<(G + 256) / 256, 256, 0, stream>>>(batch, bounds, done, N, G);
    fused_kernel<<<G * 4, 256, 0, stream>>>(x, bounds, pmax, pam, ptie, done,
                                            emb, scores);
}

// Round 11
// 231.511 us; speedup vs baseline: 12.7075x; 12.7075x over previous
//
#include <hip/hip_runtime.h>

// N=1048576 nodes, D=256 feats, G=2048 graphs, batch sorted (int32 on device).
// Out = [graph_embedding (G*256 f32), attention_scores (N f32)].
//
// R8 (best known, 237.6us) with ONE strictly-subtractive change: tie bit is
// packed into bit 30 of each per-wave argmax word (am < 2^20), deleting the
// ptie array (-17MB round-trip) and one epilogue store. No LDS combine, no
// fences, no added control flow.
//  1) bounds_kernel : bounds[g] = lower_bound(batch, g), bounds[G] = N
//  2) partial_kernel: 4 blocks/graph x 4 waves = 16 wave-slices/graph
//     (~32 contiguous rows each), 4-deep float4 prefetch ring, NT loads.
//     Per-lane stores: f32x4 max + int4 (am|tie<<30, or -1).
//  3) final_kernel  : per graph, combine 16 partials/column, write emb,
//     mark matches in scores, (rare) tie rescan, count, scale.

typedef float f32x4 __attribute__((ext_vector_type(4)));

constexpr int DIM = 256;
constexpr int WSL = 16;                 // wave-slices per graph
constexpr float NEG_CLAMP = -3.4e38f;

__device__ __forceinline__ int lower_bound_i32(const int* __restrict__ a, int n, int v) {
    int lo = 0, hi = n;
    while (lo < hi) {
        int mid = (lo + hi) >> 1;
        if (a[mid] < v) lo = mid + 1; else hi = mid;
    }
    return lo;
}

__global__ void bounds_kernel(const int* __restrict__ batch, int* __restrict__ bounds,
                              int N, int G) {
    int g = blockIdx.x * blockDim.x + threadIdx.x;
    if (g < G)  bounds[g] = lower_bound_i32(batch, N, g);
    if (g == G) bounds[G] = N;
}

__global__ __launch_bounds__(256, 8)
void partial_kernel(const float* __restrict__ x,
                    const int* __restrict__ bounds,
                    float* __restrict__ pmax,          // [G][WSL][DIM]
                    int* __restrict__ pam)             // [G][WSL][DIM] am|tie<<30, or -1
{
    const int bid = blockIdx.x;          // g*4 + s
    const int g = bid >> 2;
    const int s = bid & 3;
    const int w = threadIdx.x >> 6;
    const int l = threadIdx.x & 63;
    const int wi = s * 4 + w;            // wave-slice 0..15

    const int start = bounds[g];
    const int end   = bounds[g + 1];
    const int len   = end - start;
    const int q     = (len + WSL - 1) / WSL;

    int a = start + wi * q;
    int b = a + q;
    if (a > end) a = end;
    if (b > end) b = end;
    const int n = b - a;

    const float NI = -__builtin_huge_valf();
    float m0 = NI, m1 = NI, m2 = NI, m3 = NI;
    int   a0 = -1, a1 = -1, a2 = -1, a3 = -1;
    unsigned int tieb = 0;

    // row r (relative to a), lane l -> p[r*64]
    const f32x4* __restrict__ p = (const f32x4*)x + (size_t)a * 64 + l;

#define LD(r) __builtin_nontemporal_load(p + (size_t)(r) * 64)
#define UPD4(v, idx) do {                                             \
        bool g0 = (v).x > m0, g1 = (v).y > m1,                        \
             g2 = (v).z > m2, g3 = (v).w > m3;                        \
        tieb |= ((v).x == m0) ? 1u : 0u;                              \
        tieb |= ((v).y == m1) ? 2u : 0u;                              \
        tieb |= ((v).z == m2) ? 4u : 0u;                              \
        tieb |= ((v).w == m3) ? 8u : 0u;                              \
        a0 = g0 ? (idx) : a0;  m0 = g0 ? (v).x : m0;                  \
        a1 = g1 ? (idx) : a1;  m1 = g1 ? (v).y : m1;                  \
        a2 = g2 ? (idx) : a2;  m2 = g2 ? (v).z : m2;                  \
        a3 = g3 ? (idx) : a3;  m3 = g3 ? (v).w : m3;                  \
    } while (0)

    // 4-deep prefetch ring, statically indexed
    f32x4 f0 = (f32x4)(NI), f1 = f0, f2 = f0, f3 = f0;
    if (n > 0) f0 = LD(0);
    if (n > 1) f1 = LD(1);
    if (n > 2) f2 = LD(2);
    if (n > 3) f3 = LD(3);

    int k = 0;
    for (; k + 8 <= n; k += 4) {
        UPD4(f0, a + k + 0);  f0 = LD(k + 4);
        UPD4(f1, a + k + 1);  f1 = LD(k + 5);
        UPD4(f2, a + k + 2);  f2 = LD(k + 6);
        UPD4(f3, a + k + 3);  f3 = LD(k + 7);
    }
    const int rem = n - k;   // 0..7
    if (rem > 0) UPD4(f0, a + k + 0);
    if (rem > 1) UPD4(f1, a + k + 1);
    if (rem > 2) UPD4(f2, a + k + 2);
    if (rem > 3) UPD4(f3, a + k + 3);
    for (int r = k + 4; r < n; ++r) {
        f32x4 v = LD(r);
        UPD4(v, a + r);
    }
#undef UPD4
#undef LD

    const size_t base = ((size_t)g * WSL + wi) * DIM + (size_t)l * 4;
    f32x4 mv; mv.x = m0; mv.y = m1; mv.z = m2; mv.w = m3;
    *(f32x4*)(pmax + base) = mv;
    int4 av;
    av.x = (a0 >= 0) ? (a0 | (int)((tieb >> 0) & 1u) << 30) : -1;
    av.y = (a1 >= 0) ? (a1 | (int)((tieb >> 1) & 1u) << 30) : -1;
    av.z = (a2 >= 0) ? (a2 | (int)((tieb >> 2) & 1u) << 30) : -1;
    av.w = (a3 >= 0) ? (a3 | (int)((tieb >> 3) & 1u) << 30) : -1;
    *(int4*)(pam + base) = av;
}

__global__ __launch_bounds__(256, 8)
void final_kernel(const float* __restrict__ x,
                  const int* __restrict__ bounds,
                  const float* __restrict__ pmax,
                  const int* __restrict__ pam,
                  float* __restrict__ emb,
                  float* __restrict__ scores)
{
    const int g = blockIdx.x;
    const int t = threadIdx.x;
    const int start = bounds[g];
    const int end   = bounds[g + 1];

    // zero this graph's scores region
    for (int j = start + t; j < end; j += DIM) scores[j] = 0.0f;

    // combine 16 partials for column t
    const size_t pb = (size_t)g * WSL * DIM + t;
    float pv[WSL];
    #pragma unroll
    for (int i = 0; i < WSL; ++i) pv[i] = pmax[pb + (size_t)i * DIM];

    float M = -__builtin_huge_valf();
    #pragma unroll
    for (int i = 0; i < WSL; ++i) M = fmaxf(M, pv[i]);
    emb[(size_t)g * DIM + t] = fmaxf(M, NEG_CLAMP);

    __syncthreads();   // zeros visible before marking

    bool rescan = false;
    #pragma unroll
    for (int i = 0; i < WSL; ++i) {
        if (pv[i] == M) {
            const int pk = pam[pb + (size_t)i * DIM];
            if (pk != -1) {
                scores[pk & 0x3FFFFFFF] = 1.0f;   // duplicate 1.0 stores benign
                rescan = rescan || ((((unsigned)pk) >> 30) & 1u);
            }
        }
    }
    if (rescan) {
        // rare: exact duplicate of a slice's running max in a max-attaining
        // slice; re-scan column t, mark every exact hit of the final max.
        const float* __restrict__ col = x + t;
        for (int j = start; j < end; ++j)
            if (col[(size_t)j * DIM] == M) scores[j] = 1.0f;
    }
    __syncthreads();   // all 1-writes visible before counting

    float cnt = 0.0f;
    for (int j = start + t; j < end; j += DIM) cnt += scores[j];
    for (int off = 32; off > 0; off >>= 1) cnt += __shfl_down(cnt, off, 64);

    __shared__ float sred[4];
    if ((t & 63) == 0) sred[t >> 6] = cnt;
    __syncthreads();
    const float total = sred[0] + sred[1] + sred[2] + sred[3];
    const float inv = 1.0f / fmaxf(total, 1.0f);  // exact: numerator is 0 or 1

    for (int j = start + t; j < end; j += DIM) scores[j] *= inv;
}

extern "C" void kernel_launch(void* const* d_in, const int* in_sizes, int n_in,
                              void* d_out, int out_size, void* d_ws, size_t ws_size,
                              hipStream_t stream) {
    const float* x     = (const float*)d_in[0];
    const int*   batch = (const int*)d_in[1];

    const int N  = in_sizes[1];          // 1048576
    const int Dd = in_sizes[0] / N;      // 256
    const int G  = (out_size - N) / Dd;  // 2048

    float* emb    = (float*)d_out;
    float* scores = (float*)d_out + (size_t)G * Dd;

    // workspace layout (≈67 MB; ws is ~4 GB)
    char* ws = (char*)d_ws;
    int* bounds = (int*)ws;
    size_t off = (((size_t)(G + 1) * sizeof(int)) + 1023) & ~(size_t)1023;
    float* pmax = (float*)(ws + off);  off += (size_t)G * WSL * DIM * sizeof(float);
    int*   pam  = (int*)(ws + off);

    bounds_kernel<<<(G + 256) / 256, 256, 0, stream>>>(batch, bounds, N, G);
    partial_kernel<<<G * 4, 256, 0, stream>>>(x, bounds, pmax, pam);
    final_kernel<<<G, 256, 0, stream>>>(x, bounds, pmax, pam, emb, scores);
}